// Round 7
// baseline (158.846 us; speedup 1.0000x reference)
//
#include <hip/hip_runtime.h>

// ---------------------------------------------------------------------------
// Fused 5-layer GRU (SEQ=1, h0=0) + FC for MI355X (gfx950).  Round 8.
//
// R8: the VALU floor (~106us busy, invariant R2/R4/R6/R7) is ~75% trans ops:
// 5 per h (3 v_exp + 2 v_rcp) x 8 h x 5 layers = 200/tile x ~16cy.  Remove
// the two v_rcp sites with a division-free magic+Newton reciprocal
// (seed as_float(0x7EF311C3 - as_int(d)), 3 Newton steps -> 6e-8 rel, all
// v_pk_fma/mul), and fold the exp2 argument scales into the staged weights
// (r,z gates x -log2e; n gate x -2log2e) so MFMA output feeds exp2 directly.
// Expected: VALU busy 106 -> ~86us.  This also A/Bs the trans-cost model
// (16cy/wave64): if busy only drops ~10us, trans is 8cy and we pivot.
//
// Kept from R7: 2-tile interleave per wave (ILP), shared A-frag/bias LDS
// reads with MFMA D!=C bias init, permlane C->B transform (no LDS round
// trip), W_ST=40 padded weights (conflict-free), v_cvt_pk_bf16_f32 split,
// split-B bf16 hi+lo precision, launch_bounds(512,4) no-spill regime.
//
// Orientation: C^T = W @ h^T  (A = weight tile [gate][k], B = h^T [k][batch]).
// MFMA C/D layout (16x16x32): col = lane&15 = BATCH, row = q*4+i = gate row.
// ---------------------------------------------------------------------------

typedef __attribute__((ext_vector_type(8))) short bf16x8;
typedef __attribute__((ext_vector_type(4))) float f32x4;
typedef __attribute__((ext_vector_type(2))) float f32x2;
typedef __attribute__((ext_vector_type(4))) unsigned int u32x4;

#define NLAYER 5
#define W_ST   40  // weight row stride in bf16 (80 B = 5 bank-quads: conflict-free)
#define NT     512 // block threads (8 waves)

__device__ __forceinline__ float fexp2(float x) {
#if __has_builtin(__builtin_amdgcn_exp2f)
    return __builtin_amdgcn_exp2f(x);
#else
    return exp2f(x);
#endif
}

__device__ __forceinline__ unsigned short bf_rne(float f) {
    union { float f; unsigned u; } v; v.f = f;
    unsigned r = v.u + 0x7fffu + ((v.u >> 16) & 1u);
    return (unsigned short)(r >> 16);
}

// split via v_cvt_pk_bf16_f32: f ~= bf16(hi) + bf16(lo), two elements packed
// per word (low short = even element).  RNE hi -> |residual| <= 2^-9|f|,
// combined error ~2^-18: far below the 2^-8 weight quant floor.
__device__ __forceinline__ void split2(float f0, float f1, unsigned &hi, unsigned &lo) {
    unsigned h, l;
    asm("v_cvt_pk_bf16_f32 %0, %1, %2" : "=v"(h) : "v"(f0), "v"(f1));
    float g0 = __uint_as_float(h << 16);
    float g1 = __uint_as_float(h & 0xffff0000u);
    float r0 = f0 - g0;
    float r1 = f1 - g1;
    asm("v_cvt_pk_bf16_f32 %0, %1, %2" : "=v"(l) : "v"(r0), "v"(r1));
    hi = h; lo = l;
}

__device__ __forceinline__ f32x4 mfma16(bf16x8 a, bf16x8 b, f32x4 c) {
    return __builtin_amdgcn_mfma_f32_16x16x32_bf16(a, b, c, 0, 0, 0);
}

// In-register 16-lane-group exchange (gfx950):
//   in : x = [X0,X1,X2,X3], y = [Y0,Y1,Y2,Y3]   (16-lane groups)
//   out: x = [X0,X2,Y0,Y2], y = [X1,X3,Y1,Y3]
__device__ __forceinline__ void xpose_pair(unsigned &x, unsigned &y) {
    asm("v_permlane32_swap_b32 %0, %1" : "+v"(x), "+v"(y));
    asm("v_permlane16_swap_b32 %0, %1" : "+v"(x), "+v"(y));
}

__device__ __forceinline__ f32x2 mk2(float a, float b) { f32x2 v; v.x = a; v.y = b; return v; }
__device__ __forceinline__ f32x2 exp2v(f32x2 v) { f32x2 r; r.x = fexp2(v.x); r.y = fexp2(v.y); return r; }

// Division-free reciprocal: magic-constant seed (rel err <= ~12%) + 3 Newton
// steps -> ~6e-8 rel.  Packs as v_pk_fma/v_pk_mul (no trans pipe).
// Valid for d in (1, ~1e10) -- our denominators 1+e and (1+ez)(1+en).
__device__ __forceinline__ f32x2 rcpv(f32x2 d) {
    f32x2 y;
    y.x = __uint_as_float(0x7EF311C3u - __float_as_uint(d.x));
    y.y = __uint_as_float(0x7EF311C3u - __float_as_uint(d.y));
    #pragma unroll
    for (int i = 0; i < 3; ++i) {
        f32x2 e = 2.0f - d * y;   // contracts to v_pk_fma(-d, y, 2)
        y = y * e;
    }
    return y;
}

// h = (1-z)*n = sigmoid(-az)*tanh(an + sigmoid(ar)*cn)
//   = [ez*(1-en)] / [(1+ez)*(1+en)]
// Args are PRE-SCALED at staging: ar,az by -log2e; an,cn by -2log2e, so
// ez = exp2(az'), er = exp2(ar'), en = exp2(an' + r*cn') directly.
__device__ __forceinline__ f32x2 gru_act2(f32x2 ar, f32x2 az, f32x2 an, f32x2 cn) {
    f32x2 er  = exp2v(ar);
    f32x2 ez  = exp2v(az);
    f32x2 r   = rcpv(er + 1.0f);
    f32x2 a2  = an + r * cn;
    f32x2 en  = exp2v(a2);
    f32x2 num = ez - ez * en;
    f32x2 den = (ez + 1.0f) * (en + 1.0f);
    return num * rcpv(den);
}

struct __align__(16) Lds {
    unsigned short wA[NLAYER * 96 * W_ST];        // 38400 B  [l][gate-row][k], row stride 40
    unsigned short wF[32 * W_ST];                 //  2560 B  fc_w rows, stride 40
    float bsum[NLAYER * 96];                      //  1920 B  scaled biases
    float cn_[NLAYER * 32];                       //   640 B  scaled b_hh n-gate
    float fb_[32];                                //   128 B  fc_b
};                                                // total 43648 B

union BU { u32x4 w; bf16x8 v; };

__global__ __launch_bounds__(NT, 4) void gru_fused(
    const float* __restrict__ x, const float* __restrict__ w_ih,
    const float* __restrict__ b_ih, const float* __restrict__ b_hh,
    const float* __restrict__ fc_w, const float* __restrict__ fc_b,
    float* __restrict__ out, int nPairs)
{
    __shared__ Lds s;
    const int tid = threadIdx.x;
    const float NL2E = -1.4426950408889634f;  // -log2(e)

    // ---- stage weights / biases into LDS (once per block), pre-scaled ----
    for (int i = tid; i < NLAYER * 96 * 32; i += NT) {
        int r = i >> 5, c = i & 31;
        int g = r % 96;                         // gate row within layer
        float sc = (g < 64) ? NL2E : 2.0f * NL2E;
        s.wA[r * W_ST + c] = bf_rne(w_ih[i] * sc);
    }
    for (int i = tid; i < 32 * 32; i += NT) {
        int r = i >> 5, c = i & 31;
        s.wF[r * W_ST + c] = bf_rne(fc_w[i]);   // FC not scaled
    }
    for (int i = tid; i < NLAYER * 96; i += NT) {
        int c = i % 96;
        float v = b_ih[i] + (c < 64 ? b_hh[i] : 0.0f);
        s.bsum[i] = v * ((c < 64) ? NL2E : 2.0f * NL2E);
    }
    for (int i = tid; i < NLAYER * 32; i += NT) {
        int l = i >> 5, c = i & 31;
        s.cn_[i] = b_hh[l * 96 + 64 + c] * (2.0f * NL2E);
    }
    if (tid < 32) s.fb_[tid] = fc_b[tid];
    __syncthreads();

    const int lane = tid & 63;
    const int n0 = lane & 15;     // batch-col (B n-index / C col); A row m
    const int q  = lane >> 4;     // k-group (A/B), row-group (C/D)

    const int waveId  = (int)((blockIdx.x * (unsigned)NT + tid) >> 6);
    const int nWavesG = (int)((gridDim.x * (unsigned)NT) >> 6);

    for (int t = waveId; t < nPairs; t += nWavesG) {
        const int rowBase = t * 32;  // tile A rows +0..15, tile B rows +16..31

        // ---- load x as B-frags for both tiles, split hi/lo ----
        const float* xpA = x + (size_t)(rowBase + n0) * 32 + q * 8;
        const float* xpB = x + (size_t)(rowBase + 16 + n0) * 32 + q * 8;
        f32x4 xaA = *(const f32x4*)xpA, xbA = *(const f32x4*)(xpA + 4);
        f32x4 xaB = *(const f32x4*)xpB, xbB = *(const f32x4*)(xpB + 4);
        BU HA, LA, HB, LB;
        {
            unsigned h0, l0, h1, l1, h2, l2, h3, l3;
            split2(xaA[0], xaA[1], h0, l0); split2(xaA[2], xaA[3], h1, l1);
            split2(xbA[0], xbA[1], h2, l2); split2(xbA[2], xbA[3], h3, l3);
            HA.w[0] = h0; HA.w[1] = h1; HA.w[2] = h2; HA.w[3] = h3;
            LA.w[0] = l0; LA.w[1] = l1; LA.w[2] = l2; LA.w[3] = l3;
            split2(xaB[0], xaB[1], h0, l0); split2(xaB[2], xaB[3], h1, l1);
            split2(xbB[0], xbB[1], h2, l2); split2(xbB[2], xbB[3], h3, l3);
            HB.w[0] = h0; HB.w[1] = h1; HB.w[2] = h2; HB.w[3] = h3;
            LB.w[0] = l0; LB.w[1] = l1; LB.w[2] = l2; LB.w[3] = l3;
        }
        bf16x8 bHiA = HA.v, bLoA = LA.v, bHiB = HB.v, bLoB = LB.v;

        #pragma unroll
        for (int l = 0; l < NLAYER; ++l) {
            const unsigned short* wb = s.wA + l * 96 * W_ST;
            const float* bs = s.bsum + l * 96;

            f32x4 cR0A, cR1A, cZ0A, cZ1A, cN0A, cN1A;
            f32x4 cR0B, cR1B, cZ0B, cZ1B, cN0B, cN1B;

            // per gate-tile: 1 A-frag LDS read + 1 bias LDS read -> 4 MFMAs.
            // first MFMA uses D != C to init from the shared bias register.
            {
                bf16x8 a = *(const bf16x8*)(wb + (0 * 16 + n0) * W_ST + q * 8);
                f32x4 cb = *(const f32x4*)(bs + 0 + q * 4);
                cR0A = mfma16(a, bLoA, cb); cR0A = mfma16(a, bHiA, cR0A);
                cR0B = mfma16(a, bLoB, cb); cR0B = mfma16(a, bHiB, cR0B);
            }
            {
                bf16x8 a = *(const bf16x8*)(wb + (1 * 16 + n0) * W_ST + q * 8);
                f32x4 cb = *(const f32x4*)(bs + 16 + q * 4);
                cR1A = mfma16(a, bLoA, cb); cR1A = mfma16(a, bHiA, cR1A);
                cR1B = mfma16(a, bLoB, cb); cR1B = mfma16(a, bHiB, cR1B);
            }
            {
                bf16x8 a = *(const bf16x8*)(wb + (2 * 16 + n0) * W_ST + q * 8);
                f32x4 cb = *(const f32x4*)(bs + 32 + q * 4);
                cZ0A = mfma16(a, bLoA, cb); cZ0A = mfma16(a, bHiA, cZ0A);
                cZ0B = mfma16(a, bLoB, cb); cZ0B = mfma16(a, bHiB, cZ0B);
            }
            {
                bf16x8 a = *(const bf16x8*)(wb + (3 * 16 + n0) * W_ST + q * 8);
                f32x4 cb = *(const f32x4*)(bs + 48 + q * 4);
                cZ1A = mfma16(a, bLoA, cb); cZ1A = mfma16(a, bHiA, cZ1A);
                cZ1B = mfma16(a, bLoB, cb); cZ1B = mfma16(a, bHiB, cZ1B);
            }
            {
                bf16x8 a = *(const bf16x8*)(wb + (4 * 16 + n0) * W_ST + q * 8);
                f32x4 cb = *(const f32x4*)(bs + 64 + q * 4);
                cN0A = mfma16(a, bLoA, cb); cN0A = mfma16(a, bHiA, cN0A);
                cN0B = mfma16(a, bLoB, cb); cN0B = mfma16(a, bHiB, cN0B);
            }
            {
                bf16x8 a = *(const bf16x8*)(wb + (5 * 16 + n0) * W_ST + q * 8);
                f32x4 cb = *(const f32x4*)(bs + 80 + q * 4);
                cN1A = mfma16(a, bLoA, cb); cN1A = mfma16(a, bHiA, cN1A);
                cN1B = mfma16(a, bLoB, cb); cN1B = mfma16(a, bHiB, cN1B);
            }

            f32x4 vc0 = *(const f32x4*)(s.cn_ + l * 32 + 0  + q * 4);
            f32x4 vc1 = *(const f32x4*)(s.cn_ + l * 32 + 16 + q * 4);

            // ---- activations + pack + permlane transform, tile A ----
            {
                f32x2 hA = gru_act2(mk2(cR0A[0], cR0A[1]), mk2(cZ0A[0], cZ0A[1]),
                                    mk2(cN0A[0], cN0A[1]), mk2(vc0[0], vc0[1]));
                f32x2 hB = gru_act2(mk2(cR0A[2], cR0A[3]), mk2(cZ0A[2], cZ0A[3]),
                                    mk2(cN0A[2], cN0A[3]), mk2(vc0[2], vc0[3]));
                f32x2 hC = gru_act2(mk2(cR1A[0], cR1A[1]), mk2(cZ1A[0], cZ1A[1]),
                                    mk2(cN1A[0], cN1A[1]), mk2(vc1[0], vc1[1]));
                f32x2 hD = gru_act2(mk2(cR1A[2], cR1A[3]), mk2(cZ1A[2], cZ1A[3]),
                                    mk2(cN1A[2], cN1A[3]), mk2(vc1[2], vc1[3]));
                unsigned hw0, hw1, hw2, hw3, lw0, lw1, lw2, lw3;
                split2(hA.x, hA.y, hw0, lw0);
                split2(hB.x, hB.y, hw1, lw1);
                split2(hC.x, hC.y, hw2, lw2);
                split2(hD.x, hD.y, hw3, lw3);
                xpose_pair(hw0, hw2); xpose_pair(hw1, hw3);
                xpose_pair(lw0, lw2); xpose_pair(lw1, lw3);
                HA.w[0] = hw0; HA.w[1] = hw1; HA.w[2] = hw2; HA.w[3] = hw3;
                LA.w[0] = lw0; LA.w[1] = lw1; LA.w[2] = lw2; LA.w[3] = lw3;
                bHiA = HA.v; bLoA = LA.v;
            }
            // ---- activations + pack + permlane transform, tile B ----
            {
                f32x2 hA = gru_act2(mk2(cR0B[0], cR0B[1]), mk2(cZ0B[0], cZ0B[1]),
                                    mk2(cN0B[0], cN0B[1]), mk2(vc0[0], vc0[1]));
                f32x2 hB = gru_act2(mk2(cR0B[2], cR0B[3]), mk2(cZ0B[2], cZ0B[3]),
                                    mk2(cN0B[2], cN0B[3]), mk2(vc0[2], vc0[3]));
                f32x2 hC = gru_act2(mk2(cR1B[0], cR1B[1]), mk2(cZ1B[0], cZ1B[1]),
                                    mk2(cN1B[0], cN1B[1]), mk2(vc1[0], vc1[1]));
                f32x2 hD = gru_act2(mk2(cR1B[2], cR1B[3]), mk2(cZ1B[2], cZ1B[3]),
                                    mk2(cN1B[2], cN1B[3]), mk2(vc1[2], vc1[3]));
                unsigned hw0, hw1, hw2, hw3, lw0, lw1, lw2, lw3;
                split2(hA.x, hA.y, hw0, lw0);
                split2(hB.x, hB.y, hw1, lw1);
                split2(hC.x, hC.y, hw2, lw2);
                split2(hD.x, hD.y, hw3, lw3);
                xpose_pair(hw0, hw2); xpose_pair(hw1, hw3);
                xpose_pair(lw0, lw2); xpose_pair(lw1, lw3);
                HB.w[0] = hw0; HB.w[1] = hw1; HB.w[2] = hw2; HB.w[3] = hw3;
                LB.w[0] = lw0; LB.w[1] = lw1; LB.w[2] = lw2; LB.w[3] = lw3;
                bHiB = HB.v; bLoB = LB.v;
            }
        }

        // ---- FC: out^T = fc_w @ h5^T + fc_b, both tiles ----
        bf16x8 f0 = *(const bf16x8*)(s.wF + (0  + n0) * W_ST + q * 8);
        bf16x8 f1 = *(const bf16x8*)(s.wF + (16 + n0) * W_ST + q * 8);
        f32x4 ob0 = *(const f32x4*)(s.fb_ + 0  + q * 4);
        f32x4 ob1 = *(const f32x4*)(s.fb_ + 16 + q * 4);
        f32x4 o0A = mfma16(f0, bLoA, ob0); o0A = mfma16(f0, bHiA, o0A);
        f32x4 o1A = mfma16(f1, bLoA, ob1); o1A = mfma16(f1, bHiA, o1A);
        f32x4 o0B = mfma16(f0, bLoB, ob0); o0B = mfma16(f0, bHiB, o0B);
        f32x4 o1B = mfma16(f1, bLoB, ob1); o1B = mfma16(f1, bHiB, o1B);

        // lane holds out[batch][emb = t*16 + q*4 + i]
        float* opA = out + (size_t)(rowBase + n0) * 32;
        float* opB = out + (size_t)(rowBase + 16 + n0) * 32;
        *(f32x4*)(opA + 0  + q * 4) = o0A;
        *(f32x4*)(opA + 16 + q * 4) = o1A;
        *(f32x4*)(opB + 0  + q * 4) = o0B;
        *(f32x4*)(opB + 16 + q * 4) = o1B;
    }
}

extern "C" void kernel_launch(void* const* d_in, const int* in_sizes, int n_in,
                              void* d_out, int out_size, void* d_ws, size_t ws_size,
                              hipStream_t stream) {
    (void)n_in; (void)d_ws; (void)ws_size; (void)out_size;
    const float* x    = (const float*)d_in[0];
    const float* w_ih = (const float*)d_in[1];
    // d_in[2] = w_hh: unused (h0 == 0, T == 1)
    const float* b_ih = (const float*)d_in[3];
    const float* b_hh = (const float*)d_in[4];
    const float* fc_w = (const float*)d_in[5];
    const float* fc_b = (const float*)d_in[6];
    float* out = (float*)d_out;

    const int batch  = in_sizes[0] / 32;   // 1048576
    const int nPairs = batch / 32;         // 32768 tile-pairs (2 x 16 rows)

    // 512 blocks x 512 thr: 2 blocks/CU, 4096 waves, 8 pairs/wave.
    gru_fused<<<512, NT, 0, stream>>>(x, w_ih, b_ih, b_hh, fc_w, fc_b, out, nPairs);
}

// Round 8
// 132.165 us; speedup vs baseline: 1.2019x; 1.2019x over previous
//
#include <hip/hip_runtime.h>

// ---------------------------------------------------------------------------
// Fused 5-layer GRU (SEQ=1, h0=0) + FC for MI355X (gfx950).  Round 9.
//
// R9: two changes vs R8.
//  (1) Revert the magic+Newton reciprocal to hardware v_rcp_f32.  R8's A/B
//      showed the Newton path ADDED ~16us of VALU busy: back-solving gives
//      v_rcp(wave64) ~ 4cy, so 8 pk/int ops per pair can't beat 2 trans ops.
//      (Trans ops are only ~20% of the VALU floor, not 75% as modeled.)
//  (2) Grid 512 -> 768 blocks.  LDS 43.6KB fits 3 blocks/CU (131 < 160KB),
//      arch VGPR_Count reads 44, and the old grid (2 blocks/CU exactly) was
//      what capped residency.  launch_bounds stays (512,4) so the allocator
//      cap is unchanged (no R5-style spill); if HW grants 24 waves/CU the
//      57us wall-minus-busy stall gap shrinks; if not, neutral.
// Kept from R8: exp2-scale folded into staged weights/biases.
// Kept from R7: 2-tile interleave, shared A-frag/bias reads with MFMA D!=C
// bias init, permlane C->B transform, W_ST=40 padding, cvt_pk split,
// split-B bf16 hi+lo precision.
//
// Orientation: C^T = W @ h^T  (A = weight tile [gate][k], B = h^T [k][batch]).
// MFMA C/D layout (16x16x32): col = lane&15 = BATCH, row = q*4+i = gate row.
// ---------------------------------------------------------------------------

typedef __attribute__((ext_vector_type(8))) short bf16x8;
typedef __attribute__((ext_vector_type(4))) float f32x4;
typedef __attribute__((ext_vector_type(2))) float f32x2;
typedef __attribute__((ext_vector_type(4))) unsigned int u32x4;

#define NLAYER 5
#define W_ST   40  // weight row stride in bf16 (80 B = 5 bank-quads: conflict-free)
#define NT     512 // block threads (8 waves)

__device__ __forceinline__ float fexp2(float x) {
#if __has_builtin(__builtin_amdgcn_exp2f)
    return __builtin_amdgcn_exp2f(x);
#else
    return exp2f(x);
#endif
}
__device__ __forceinline__ float frcp(float x) {
#if __has_builtin(__builtin_amdgcn_rcpf)
    return __builtin_amdgcn_rcpf(x);
#else
    return 1.0f / x;
#endif
}

__device__ __forceinline__ unsigned short bf_rne(float f) {
    union { float f; unsigned u; } v; v.f = f;
    unsigned r = v.u + 0x7fffu + ((v.u >> 16) & 1u);
    return (unsigned short)(r >> 16);
}

// split via v_cvt_pk_bf16_f32: f ~= bf16(hi) + bf16(lo), two elements packed
// per word (low short = even element).  RNE hi -> |residual| <= 2^-9|f|,
// combined error ~2^-18: far below the 2^-8 weight quant floor.
__device__ __forceinline__ void split2(float f0, float f1, unsigned &hi, unsigned &lo) {
    unsigned h, l;
    asm("v_cvt_pk_bf16_f32 %0, %1, %2" : "=v"(h) : "v"(f0), "v"(f1));
    float g0 = __uint_as_float(h << 16);
    float g1 = __uint_as_float(h & 0xffff0000u);
    float r0 = f0 - g0;
    float r1 = f1 - g1;
    asm("v_cvt_pk_bf16_f32 %0, %1, %2" : "=v"(l) : "v"(r0), "v"(r1));
    hi = h; lo = l;
}

__device__ __forceinline__ f32x4 mfma16(bf16x8 a, bf16x8 b, f32x4 c) {
    return __builtin_amdgcn_mfma_f32_16x16x32_bf16(a, b, c, 0, 0, 0);
}

// In-register 16-lane-group exchange (gfx950):
//   in : x = [X0,X1,X2,X3], y = [Y0,Y1,Y2,Y3]   (16-lane groups)
//   out: x = [X0,X2,Y0,Y2], y = [X1,X3,Y1,Y3]
__device__ __forceinline__ void xpose_pair(unsigned &x, unsigned &y) {
    asm("v_permlane32_swap_b32 %0, %1" : "+v"(x), "+v"(y));
    asm("v_permlane16_swap_b32 %0, %1" : "+v"(x), "+v"(y));
}

__device__ __forceinline__ f32x2 mk2(float a, float b) { f32x2 v; v.x = a; v.y = b; return v; }
__device__ __forceinline__ f32x2 exp2v(f32x2 v) { f32x2 r; r.x = fexp2(v.x); r.y = fexp2(v.y); return r; }
__device__ __forceinline__ f32x2 rcpv(f32x2 v)  { f32x2 r; r.x = frcp(v.x);  r.y = frcp(v.y);  return r; }

// h = (1-z)*n = sigmoid(-az)*tanh(an + sigmoid(ar)*cn)
//   = [ez*(1-en)] / [(1+ez)*(1+en)]
// Args are PRE-SCALED at staging: ar,az by -log2e; an,cn by -2log2e, so
// er = exp2(ar'), ez = exp2(az'), en = exp2(an' + r*cn') directly.
__device__ __forceinline__ f32x2 gru_act2(f32x2 ar, f32x2 az, f32x2 an, f32x2 cn) {
    f32x2 er  = exp2v(ar);
    f32x2 ez  = exp2v(az);
    f32x2 r   = rcpv(er + 1.0f);
    f32x2 a2  = an + r * cn;
    f32x2 en  = exp2v(a2);
    f32x2 num = ez - ez * en;
    f32x2 den = (ez + 1.0f) * (en + 1.0f);
    return num * rcpv(den);
}

struct __align__(16) Lds {
    unsigned short wA[NLAYER * 96 * W_ST];        // 38400 B  [l][gate-row][k], row stride 40
    unsigned short wF[32 * W_ST];                 //  2560 B  fc_w rows, stride 40
    float bsum[NLAYER * 96];                      //  1920 B  scaled biases
    float cn_[NLAYER * 32];                       //   640 B  scaled b_hh n-gate
    float fb_[32];                                //   128 B  fc_b
};                                                // total 43648 B -> 3 blocks/CU by LDS

union BU { u32x4 w; bf16x8 v; };

__global__ __launch_bounds__(NT, 4) void gru_fused(
    const float* __restrict__ x, const float* __restrict__ w_ih,
    const float* __restrict__ b_ih, const float* __restrict__ b_hh,
    const float* __restrict__ fc_w, const float* __restrict__ fc_b,
    float* __restrict__ out, int nPairs)
{
    __shared__ Lds s;
    const int tid = threadIdx.x;
    const float NL2E = -1.4426950408889634f;  // -log2(e)

    // ---- stage weights / biases into LDS (once per block), pre-scaled ----
    for (int i = tid; i < NLAYER * 96 * 32; i += NT) {
        int r = i >> 5, c = i & 31;
        int g = r % 96;                         // gate row within layer
        float sc = (g < 64) ? NL2E : 2.0f * NL2E;
        s.wA[r * W_ST + c] = bf_rne(w_ih[i] * sc);
    }
    for (int i = tid; i < 32 * 32; i += NT) {
        int r = i >> 5, c = i & 31;
        s.wF[r * W_ST + c] = bf_rne(fc_w[i]);   // FC not scaled
    }
    for (int i = tid; i < NLAYER * 96; i += NT) {
        int c = i % 96;
        float v = b_ih[i] + (c < 64 ? b_hh[i] : 0.0f);
        s.bsum[i] = v * ((c < 64) ? NL2E : 2.0f * NL2E);
    }
    for (int i = tid; i < NLAYER * 32; i += NT) {
        int l = i >> 5, c = i & 31;
        s.cn_[i] = b_hh[l * 96 + 64 + c] * (2.0f * NL2E);
    }
    if (tid < 32) s.fb_[tid] = fc_b[tid];
    __syncthreads();

    const int lane = tid & 63;
    const int n0 = lane & 15;     // batch-col (B n-index / C col); A row m
    const int q  = lane >> 4;     // k-group (A/B), row-group (C/D)

    const int waveId  = (int)((blockIdx.x * (unsigned)NT + tid) >> 6);
    const int nWavesG = (int)((gridDim.x * (unsigned)NT) >> 6);

    for (int t = waveId; t < nPairs; t += nWavesG) {
        const int rowBase = t * 32;  // tile A rows +0..15, tile B rows +16..31

        // ---- load x as B-frags for both tiles, split hi/lo ----
        const float* xpA = x + (size_t)(rowBase + n0) * 32 + q * 8;
        const float* xpB = x + (size_t)(rowBase + 16 + n0) * 32 + q * 8;
        f32x4 xaA = *(const f32x4*)xpA, xbA = *(const f32x4*)(xpA + 4);
        f32x4 xaB = *(const f32x4*)xpB, xbB = *(const f32x4*)(xpB + 4);
        BU HA, LA, HB, LB;
        {
            unsigned h0, l0, h1, l1, h2, l2, h3, l3;
            split2(xaA[0], xaA[1], h0, l0); split2(xaA[2], xaA[3], h1, l1);
            split2(xbA[0], xbA[1], h2, l2); split2(xbA[2], xbA[3], h3, l3);
            HA.w[0] = h0; HA.w[1] = h1; HA.w[2] = h2; HA.w[3] = h3;
            LA.w[0] = l0; LA.w[1] = l1; LA.w[2] = l2; LA.w[3] = l3;
            split2(xaB[0], xaB[1], h0, l0); split2(xaB[2], xaB[3], h1, l1);
            split2(xbB[0], xbB[1], h2, l2); split2(xbB[2], xbB[3], h3, l3);
            HB.w[0] = h0; HB.w[1] = h1; HB.w[2] = h2; HB.w[3] = h3;
            LB.w[0] = l0; LB.w[1] = l1; LB.w[2] = l2; LB.w[3] = l3;
        }
        bf16x8 bHiA = HA.v, bLoA = LA.v, bHiB = HB.v, bLoB = LB.v;

        #pragma unroll
        for (int l = 0; l < NLAYER; ++l) {
            const unsigned short* wb = s.wA + l * 96 * W_ST;
            const float* bs = s.bsum + l * 96;

            f32x4 cR0A, cR1A, cZ0A, cZ1A, cN0A, cN1A;
            f32x4 cR0B, cR1B, cZ0B, cZ1B, cN0B, cN1B;

            // per gate-tile: 1 A-frag LDS read + 1 bias LDS read -> 4 MFMAs.
            // first MFMA uses D != C to init from the shared bias register.
            {
                bf16x8 a = *(const bf16x8*)(wb + (0 * 16 + n0) * W_ST + q * 8);
                f32x4 cb = *(const f32x4*)(bs + 0 + q * 4);
                cR0A = mfma16(a, bLoA, cb); cR0A = mfma16(a, bHiA, cR0A);
                cR0B = mfma16(a, bLoB, cb); cR0B = mfma16(a, bHiB, cR0B);
            }
            {
                bf16x8 a = *(const bf16x8*)(wb + (1 * 16 + n0) * W_ST + q * 8);
                f32x4 cb = *(const f32x4*)(bs + 16 + q * 4);
                cR1A = mfma16(a, bLoA, cb); cR1A = mfma16(a, bHiA, cR1A);
                cR1B = mfma16(a, bLoB, cb); cR1B = mfma16(a, bHiB, cR1B);
            }
            {
                bf16x8 a = *(const bf16x8*)(wb + (2 * 16 + n0) * W_ST + q * 8);
                f32x4 cb = *(const f32x4*)(bs + 32 + q * 4);
                cZ0A = mfma16(a, bLoA, cb); cZ0A = mfma16(a, bHiA, cZ0A);
                cZ0B = mfma16(a, bLoB, cb); cZ0B = mfma16(a, bHiB, cZ0B);
            }
            {
                bf16x8 a = *(const bf16x8*)(wb + (3 * 16 + n0) * W_ST + q * 8);
                f32x4 cb = *(const f32x4*)(bs + 48 + q * 4);
                cZ1A = mfma16(a, bLoA, cb); cZ1A = mfma16(a, bHiA, cZ1A);
                cZ1B = mfma16(a, bLoB, cb); cZ1B = mfma16(a, bHiB, cZ1B);
            }
            {
                bf16x8 a = *(const bf16x8*)(wb + (4 * 16 + n0) * W_ST + q * 8);
                f32x4 cb = *(const f32x4*)(bs + 64 + q * 4);
                cN0A = mfma16(a, bLoA, cb); cN0A = mfma16(a, bHiA, cN0A);
                cN0B = mfma16(a, bLoB, cb); cN0B = mfma16(a, bHiB, cN0B);
            }
            {
                bf16x8 a = *(const bf16x8*)(wb + (5 * 16 + n0) * W_ST + q * 8);
                f32x4 cb = *(const f32x4*)(bs + 80 + q * 4);
                cN1A = mfma16(a, bLoA, cb); cN1A = mfma16(a, bHiA, cN1A);
                cN1B = mfma16(a, bLoB, cb); cN1B = mfma16(a, bHiB, cN1B);
            }

            f32x4 vc0 = *(const f32x4*)(s.cn_ + l * 32 + 0  + q * 4);
            f32x4 vc1 = *(const f32x4*)(s.cn_ + l * 32 + 16 + q * 4);

            // ---- activations + pack + permlane transform, tile A ----
            {
                f32x2 hA = gru_act2(mk2(cR0A[0], cR0A[1]), mk2(cZ0A[0], cZ0A[1]),
                                    mk2(cN0A[0], cN0A[1]), mk2(vc0[0], vc0[1]));
                f32x2 hB = gru_act2(mk2(cR0A[2], cR0A[3]), mk2(cZ0A[2], cZ0A[3]),
                                    mk2(cN0A[2], cN0A[3]), mk2(vc0[2], vc0[3]));
                f32x2 hC = gru_act2(mk2(cR1A[0], cR1A[1]), mk2(cZ1A[0], cZ1A[1]),
                                    mk2(cN1A[0], cN1A[1]), mk2(vc1[0], vc1[1]));
                f32x2 hD = gru_act2(mk2(cR1A[2], cR1A[3]), mk2(cZ1A[2], cZ1A[3]),
                                    mk2(cN1A[2], cN1A[3]), mk2(vc1[2], vc1[3]));
                unsigned hw0, hw1, hw2, hw3, lw0, lw1, lw2, lw3;
                split2(hA.x, hA.y, hw0, lw0);
                split2(hB.x, hB.y, hw1, lw1);
                split2(hC.x, hC.y, hw2, lw2);
                split2(hD.x, hD.y, hw3, lw3);
                xpose_pair(hw0, hw2); xpose_pair(hw1, hw3);
                xpose_pair(lw0, lw2); xpose_pair(lw1, lw3);
                HA.w[0] = hw0; HA.w[1] = hw1; HA.w[2] = hw2; HA.w[3] = hw3;
                LA.w[0] = lw0; LA.w[1] = lw1; LA.w[2] = lw2; LA.w[3] = lw3;
                bHiA = HA.v; bLoA = LA.v;
            }
            // ---- activations + pack + permlane transform, tile B ----
            {
                f32x2 hA = gru_act2(mk2(cR0B[0], cR0B[1]), mk2(cZ0B[0], cZ0B[1]),
                                    mk2(cN0B[0], cN0B[1]), mk2(vc0[0], vc0[1]));
                f32x2 hB = gru_act2(mk2(cR0B[2], cR0B[3]), mk2(cZ0B[2], cZ0B[3]),
                                    mk2(cN0B[2], cN0B[3]), mk2(vc0[2], vc0[3]));
                f32x2 hC = gru_act2(mk2(cR1B[0], cR1B[1]), mk2(cZ1B[0], cZ1B[1]),
                                    mk2(cN1B[0], cN1B[1]), mk2(vc1[0], vc1[1]));
                f32x2 hD = gru_act2(mk2(cR1B[2], cR1B[3]), mk2(cZ1B[2], cZ1B[3]),
                                    mk2(cN1B[2], cN1B[3]), mk2(vc1[2], vc1[3]));
                unsigned hw0, hw1, hw2, hw3, lw0, lw1, lw2, lw3;
                split2(hA.x, hA.y, hw0, lw0);
                split2(hB.x, hB.y, hw1, lw1);
                split2(hC.x, hC.y, hw2, lw2);
                split2(hD.x, hD.y, hw3, lw3);
                xpose_pair(hw0, hw2); xpose_pair(hw1, hw3);
                xpose_pair(lw0, lw2); xpose_pair(lw1, lw3);
                HB.w[0] = hw0; HB.w[1] = hw1; HB.w[2] = hw2; HB.w[3] = hw3;
                LB.w[0] = lw0; LB.w[1] = lw1; LB.w[2] = lw2; LB.w[3] = lw3;
                bHiB = HB.v; bLoB = LB.v;
            }
        }

        // ---- FC: out^T = fc_w @ h5^T + fc_b, both tiles ----
        bf16x8 f0 = *(const bf16x8*)(s.wF + (0  + n0) * W_ST + q * 8);
        bf16x8 f1 = *(const bf16x8*)(s.wF + (16 + n0) * W_ST + q * 8);
        f32x4 ob0 = *(const f32x4*)(s.fb_ + 0  + q * 4);
        f32x4 ob1 = *(const f32x4*)(s.fb_ + 16 + q * 4);
        f32x4 o0A = mfma16(f0, bLoA, ob0); o0A = mfma16(f0, bHiA, o0A);
        f32x4 o1A = mfma16(f1, bLoA, ob1); o1A = mfma16(f1, bHiA, o1A);
        f32x4 o0B = mfma16(f0, bLoB, ob0); o0B = mfma16(f0, bHiB, o0B);
        f32x4 o1B = mfma16(f1, bLoB, ob1); o1B = mfma16(f1, bHiB, o1B);

        // lane holds out[batch][emb = t*16 + q*4 + i]
        float* opA = out + (size_t)(rowBase + n0) * 32;
        float* opB = out + (size_t)(rowBase + 16 + n0) * 32;
        *(f32x4*)(opA + 0  + q * 4) = o0A;
        *(f32x4*)(opA + 16 + q * 4) = o1A;
        *(f32x4*)(opB + 0  + q * 4) = o0B;
        *(f32x4*)(opB + 16 + q * 4) = o1B;
    }
}

extern "C" void kernel_launch(void* const* d_in, const int* in_sizes, int n_in,
                              void* d_out, int out_size, void* d_ws, size_t ws_size,
                              hipStream_t stream) {
    (void)n_in; (void)d_ws; (void)ws_size; (void)out_size;
    const float* x    = (const float*)d_in[0];
    const float* w_ih = (const float*)d_in[1];
    // d_in[2] = w_hh: unused (h0 == 0, T == 1)
    const float* b_ih = (const float*)d_in[3];
    const float* b_hh = (const float*)d_in[4];
    const float* fc_w = (const float*)d_in[5];
    const float* fc_b = (const float*)d_in[6];
    float* out = (float*)d_out;

    const int batch  = in_sizes[0] / 32;   // 1048576
    const int nPairs = batch / 32;         // 32768 tile-pairs (2 x 16 rows)

    // 768 blocks x 512 thr: LDS fits 3 blocks/CU (131KB); if unified VGPR
    // use permits 24 waves/CU the HW will host 3, else blocks serialize
    // (neutral).  6144 waves, ~5.3 pairs/wave grid-stride.
    gru_fused<<<768, NT, 0, stream>>>(x, w_ih, b_ih, b_hh, fc_w, fc_b, out, nPairs);
}

// Round 9
// 101.712 us; speedup vs baseline: 1.5617x; 1.2994x over previous
//
#include <hip/hip_runtime.h>

// ---------------------------------------------------------------------------
// Fused 5-layer GRU (SEQ=1, h0=0) + FC for MI355X (gfx950).  Round 10.
//
// R10: single-plane fp16 operands replace the split-bf16 hi+lo scheme.
// fp16 has 10+1 mantissa bits: weight quant error 2^-11 (vs bf16 2^-8, which
// was the 3.9e-3 absmax floor) and h/x quant ~2^-10 (RTZ pack).  So ONE
// v_mfma_f32_16x16x32_f16 per gate-tile suffices:
//  - MFMA count halves (128 -> 64 per pair)
//  - split2 (4 ops) -> one v_cvt_pkrtz_f16_f32 per pair of floats
//  - permlane transform ops halve (8 -> 4 per tile), B-frags 16 -> 8 regs
//  - absmax expected to IMPROVE to ~1e-3 (falsifiable signature)
// VALU busy (invariant ~102us since R2) predicted -> ~85-90us.
//
// Kept from R9: hardware v_rcp, exp2 scales folded into staged weights,
// grid 768 (3 blocks/CU by LDS), launch_bounds(512,4) no-spill regime.
// Kept from R7: 2-tile interleave, shared A-frag/bias reads with MFMA D!=C
// bias init, permlane C->B transform, W_ST=40 padded LDS weights.
//
// Orientation: C^T = W @ h^T  (A = weight tile [gate][k], B = h^T [k][batch]).
// MFMA C/D layout (16x16x32): col = lane&15 = BATCH, row = q*4+i = gate row.
// ---------------------------------------------------------------------------

typedef __attribute__((ext_vector_type(8))) _Float16 f16x8;
typedef __attribute__((ext_vector_type(4))) float f32x4;
typedef __attribute__((ext_vector_type(2))) float f32x2;
typedef __attribute__((ext_vector_type(4))) unsigned int u32x4;

#define NLAYER 5
#define W_ST   40  // weight row stride in fp16 (80 B = 5 bank-quads: conflict-free)
#define NT     512 // block threads (8 waves)

__device__ __forceinline__ float fexp2(float x) {
#if __has_builtin(__builtin_amdgcn_exp2f)
    return __builtin_amdgcn_exp2f(x);
#else
    return exp2f(x);
#endif
}
__device__ __forceinline__ float frcp(float x) {
#if __has_builtin(__builtin_amdgcn_rcpf)
    return __builtin_amdgcn_rcpf(x);
#else
    return 1.0f / x;
#endif
}

// pack two f32 -> two fp16 (RTZ) in one word; rel err <= 2^-10, far below
// the fp16 weight quant (2^-11 RNE) + ref tolerance.
__device__ __forceinline__ unsigned cvt2(float f0, float f1) {
    unsigned r;
    asm("v_cvt_pkrtz_f16_f32 %0, %1, %2" : "=v"(r) : "v"(f0), "v"(f1));
    return r;
}

__device__ __forceinline__ f32x4 mfma16h(f16x8 a, f16x8 b, f32x4 c) {
    return __builtin_amdgcn_mfma_f32_16x16x32_f16(a, b, c, 0, 0, 0);
}

// In-register 16-lane-group exchange (gfx950):
//   in : x = [X0,X1,X2,X3], y = [Y0,Y1,Y2,Y3]   (16-lane groups)
//   out: x = [X0,X2,Y0,Y2], y = [X1,X3,Y1,Y3]
__device__ __forceinline__ void xpose_pair(unsigned &x, unsigned &y) {
    asm("v_permlane32_swap_b32 %0, %1" : "+v"(x), "+v"(y));
    asm("v_permlane16_swap_b32 %0, %1" : "+v"(x), "+v"(y));
}

__device__ __forceinline__ f32x2 mk2(float a, float b) { f32x2 v; v.x = a; v.y = b; return v; }
__device__ __forceinline__ f32x2 exp2v(f32x2 v) { f32x2 r; r.x = fexp2(v.x); r.y = fexp2(v.y); return r; }
__device__ __forceinline__ f32x2 rcpv(f32x2 v)  { f32x2 r; r.x = frcp(v.x);  r.y = frcp(v.y);  return r; }

// h = (1-z)*n = sigmoid(-az)*tanh(an + sigmoid(ar)*cn)
//   = [ez*(1-en)] / [(1+ez)*(1+en)]
// Args are PRE-SCALED at staging: ar,az by -log2e; an,cn by -2log2e, so
// er = exp2(ar'), ez = exp2(az'), en = exp2(an' + r*cn') directly.
__device__ __forceinline__ f32x2 gru_act2(f32x2 ar, f32x2 az, f32x2 an, f32x2 cn) {
    f32x2 er  = exp2v(ar);
    f32x2 ez  = exp2v(az);
    f32x2 r   = rcpv(er + 1.0f);
    f32x2 a2  = an + r * cn;
    f32x2 en  = exp2v(a2);
    f32x2 num = ez - ez * en;
    f32x2 den = (ez + 1.0f) * (en + 1.0f);
    return num * rcpv(den);
}

struct __align__(16) Lds {
    _Float16 wA[NLAYER * 96 * W_ST];              // 38400 B  [l][gate-row][k], row stride 40
    _Float16 wF[32 * W_ST];                       //  2560 B  fc_w rows, stride 40
    float bsum[NLAYER * 96];                      //  1920 B  scaled biases
    float cn_[NLAYER * 32];                       //   640 B  scaled b_hh n-gate
    float fb_[32];                                //   128 B  fc_b
};                                                // total 43648 B -> 3 blocks/CU by LDS

union BU { u32x4 w; f16x8 v; };

__global__ __launch_bounds__(NT, 4) void gru_fused(
    const float* __restrict__ x, const float* __restrict__ w_ih,
    const float* __restrict__ b_ih, const float* __restrict__ b_hh,
    const float* __restrict__ fc_w, const float* __restrict__ fc_b,
    float* __restrict__ out, int nPairs)
{
    __shared__ Lds s;
    const int tid = threadIdx.x;
    const float NL2E = -1.4426950408889634f;  // -log2(e)

    // ---- stage weights / biases into LDS (once per block), pre-scaled ----
    for (int i = tid; i < NLAYER * 96 * 32; i += NT) {
        int r = i >> 5, c = i & 31;
        int g = r % 96;                         // gate row within layer
        float sc = (g < 64) ? NL2E : 2.0f * NL2E;
        s.wA[r * W_ST + c] = (_Float16)(w_ih[i] * sc);   // RNE, rel 2^-11
    }
    for (int i = tid; i < 32 * 32; i += NT) {
        int r = i >> 5, c = i & 31;
        s.wF[r * W_ST + c] = (_Float16)fc_w[i];          // FC not scaled
    }
    for (int i = tid; i < NLAYER * 96; i += NT) {
        int c = i % 96;
        float v = b_ih[i] + (c < 64 ? b_hh[i] : 0.0f);
        s.bsum[i] = v * ((c < 64) ? NL2E : 2.0f * NL2E);
    }
    for (int i = tid; i < NLAYER * 32; i += NT) {
        int l = i >> 5, c = i & 31;
        s.cn_[i] = b_hh[l * 96 + 64 + c] * (2.0f * NL2E);
    }
    if (tid < 32) s.fb_[tid] = fc_b[tid];
    __syncthreads();

    const int lane = tid & 63;
    const int n0 = lane & 15;     // batch-col (B n-index / C col); A row m
    const int q  = lane >> 4;     // k-group (A/B), row-group (C/D)

    const int waveId  = (int)((blockIdx.x * (unsigned)NT + tid) >> 6);
    const int nWavesG = (int)((gridDim.x * (unsigned)NT) >> 6);

    for (int t = waveId; t < nPairs; t += nWavesG) {
        const int rowBase = t * 32;  // tile A rows +0..15, tile B rows +16..31

        // ---- load x as fp16 B-frags for both tiles ----
        const float* xpA = x + (size_t)(rowBase + n0) * 32 + q * 8;
        const float* xpB = x + (size_t)(rowBase + 16 + n0) * 32 + q * 8;
        f32x4 xaA = *(const f32x4*)xpA, xbA = *(const f32x4*)(xpA + 4);
        f32x4 xaB = *(const f32x4*)xpB, xbB = *(const f32x4*)(xpB + 4);
        BU BA, BB;
        BA.w[0] = cvt2(xaA[0], xaA[1]); BA.w[1] = cvt2(xaA[2], xaA[3]);
        BA.w[2] = cvt2(xbA[0], xbA[1]); BA.w[3] = cvt2(xbA[2], xbA[3]);
        BB.w[0] = cvt2(xaB[0], xaB[1]); BB.w[1] = cvt2(xaB[2], xaB[3]);
        BB.w[2] = cvt2(xbB[0], xbB[1]); BB.w[3] = cvt2(xbB[2], xbB[3]);
        f16x8 bA = BA.v, bB = BB.v;

        #pragma unroll
        for (int l = 0; l < NLAYER; ++l) {
            const _Float16* wb = s.wA + l * 96 * W_ST;
            const float* bs = s.bsum + l * 96;

            f32x4 cR0A, cR1A, cZ0A, cZ1A, cN0A, cN1A;
            f32x4 cR0B, cR1B, cZ0B, cZ1B, cN0B, cN1B;

            // per gate-tile: 1 A-frag LDS read + 1 bias LDS read -> 2 MFMAs
            // (one per batch-tile), each initing from bias via D != C.
            {
                f16x8 a = *(const f16x8*)(wb + (0 * 16 + n0) * W_ST + q * 8);
                f32x4 cb = *(const f32x4*)(bs + 0 + q * 4);
                cR0A = mfma16h(a, bA, cb);
                cR0B = mfma16h(a, bB, cb);
            }
            {
                f16x8 a = *(const f16x8*)(wb + (1 * 16 + n0) * W_ST + q * 8);
                f32x4 cb = *(const f32x4*)(bs + 16 + q * 4);
                cR1A = mfma16h(a, bA, cb);
                cR1B = mfma16h(a, bB, cb);
            }
            {
                f16x8 a = *(const f16x8*)(wb + (2 * 16 + n0) * W_ST + q * 8);
                f32x4 cb = *(const f32x4*)(bs + 32 + q * 4);
                cZ0A = mfma16h(a, bA, cb);
                cZ0B = mfma16h(a, bB, cb);
            }
            {
                f16x8 a = *(const f16x8*)(wb + (3 * 16 + n0) * W_ST + q * 8);
                f32x4 cb = *(const f32x4*)(bs + 48 + q * 4);
                cZ1A = mfma16h(a, bA, cb);
                cZ1B = mfma16h(a, bB, cb);
            }
            {
                f16x8 a = *(const f16x8*)(wb + (4 * 16 + n0) * W_ST + q * 8);
                f32x4 cb = *(const f32x4*)(bs + 64 + q * 4);
                cN0A = mfma16h(a, bA, cb);
                cN0B = mfma16h(a, bB, cb);
            }
            {
                f16x8 a = *(const f16x8*)(wb + (5 * 16 + n0) * W_ST + q * 8);
                f32x4 cb = *(const f32x4*)(bs + 80 + q * 4);
                cN1A = mfma16h(a, bA, cb);
                cN1B = mfma16h(a, bB, cb);
            }

            f32x4 vc0 = *(const f32x4*)(s.cn_ + l * 32 + 0  + q * 4);
            f32x4 vc1 = *(const f32x4*)(s.cn_ + l * 32 + 16 + q * 4);

            // ---- activations + pack + permlane transform, tile A ----
            {
                f32x2 hA = gru_act2(mk2(cR0A[0], cR0A[1]), mk2(cZ0A[0], cZ0A[1]),
                                    mk2(cN0A[0], cN0A[1]), mk2(vc0[0], vc0[1]));
                f32x2 hB = gru_act2(mk2(cR0A[2], cR0A[3]), mk2(cZ0A[2], cZ0A[3]),
                                    mk2(cN0A[2], cN0A[3]), mk2(vc0[2], vc0[3]));
                f32x2 hC = gru_act2(mk2(cR1A[0], cR1A[1]), mk2(cZ1A[0], cZ1A[1]),
                                    mk2(cN1A[0], cN1A[1]), mk2(vc1[0], vc1[1]));
                f32x2 hD = gru_act2(mk2(cR1A[2], cR1A[3]), mk2(cZ1A[2], cZ1A[3]),
                                    mk2(cN1A[2], cN1A[3]), mk2(vc1[2], vc1[3]));
                unsigned hw0 = cvt2(hA.x, hA.y);   // hids 4q+{0,1}
                unsigned hw1 = cvt2(hB.x, hB.y);   // hids 4q+{2,3}
                unsigned hw2 = cvt2(hC.x, hC.y);   // hids 16+4q+{0,1}
                unsigned hw3 = cvt2(hD.x, hD.y);   // hids 16+4q+{2,3}
                xpose_pair(hw0, hw2);   // hw0 -> B elems {0,1}, hw2 -> {4,5}
                xpose_pair(hw1, hw3);   // hw1 -> B elems {2,3}, hw3 -> {6,7}
                BA.w[0] = hw0; BA.w[1] = hw1; BA.w[2] = hw2; BA.w[3] = hw3;
                bA = BA.v;
            }
            // ---- activations + pack + permlane transform, tile B ----
            {
                f32x2 hA = gru_act2(mk2(cR0B[0], cR0B[1]), mk2(cZ0B[0], cZ0B[1]),
                                    mk2(cN0B[0], cN0B[1]), mk2(vc0[0], vc0[1]));
                f32x2 hB = gru_act2(mk2(cR0B[2], cR0B[3]), mk2(cZ0B[2], cZ0B[3]),
                                    mk2(cN0B[2], cN0B[3]), mk2(vc0[2], vc0[3]));
                f32x2 hC = gru_act2(mk2(cR1B[0], cR1B[1]), mk2(cZ1B[0], cZ1B[1]),
                                    mk2(cN1B[0], cN1B[1]), mk2(vc1[0], vc1[1]));
                f32x2 hD = gru_act2(mk2(cR1B[2], cR1B[3]), mk2(cZ1B[2], cZ1B[3]),
                                    mk2(cN1B[2], cN1B[3]), mk2(vc1[2], vc1[3]));
                unsigned hw0 = cvt2(hA.x, hA.y);
                unsigned hw1 = cvt2(hB.x, hB.y);
                unsigned hw2 = cvt2(hC.x, hC.y);
                unsigned hw3 = cvt2(hD.x, hD.y);
                xpose_pair(hw0, hw2);
                xpose_pair(hw1, hw3);
                BB.w[0] = hw0; BB.w[1] = hw1; BB.w[2] = hw2; BB.w[3] = hw3;
                bB = BB.v;
            }
        }

        // ---- FC: out^T = fc_w @ h5^T + fc_b, both tiles ----
        f16x8 f0 = *(const f16x8*)(s.wF + (0  + n0) * W_ST + q * 8);
        f16x8 f1 = *(const f16x8*)(s.wF + (16 + n0) * W_ST + q * 8);
        f32x4 ob0 = *(const f32x4*)(s.fb_ + 0  + q * 4);
        f32x4 ob1 = *(const f32x4*)(s.fb_ + 16 + q * 4);
        f32x4 o0A = mfma16h(f0, bA, ob0);
        f32x4 o1A = mfma16h(f1, bA, ob1);
        f32x4 o0B = mfma16h(f0, bB, ob0);
        f32x4 o1B = mfma16h(f1, bB, ob1);

        // lane holds out[batch][emb = t*16 + q*4 + i]
        float* opA = out + (size_t)(rowBase + n0) * 32;
        float* opB = out + (size_t)(rowBase + 16 + n0) * 32;
        *(f32x4*)(opA + 0  + q * 4) = o0A;
        *(f32x4*)(opA + 16 + q * 4) = o1A;
        *(f32x4*)(opB + 0  + q * 4) = o0B;
        *(f32x4*)(opB + 16 + q * 4) = o1B;
    }
}

extern "C" void kernel_launch(void* const* d_in, const int* in_sizes, int n_in,
                              void* d_out, int out_size, void* d_ws, size_t ws_size,
                              hipStream_t stream) {
    (void)n_in; (void)d_ws; (void)ws_size; (void)out_size;
    const float* x    = (const float*)d_in[0];
    const float* w_ih = (const float*)d_in[1];
    // d_in[2] = w_hh: unused (h0 == 0, T == 1)
    const float* b_ih = (const float*)d_in[3];
    const float* b_hh = (const float*)d_in[4];
    const float* fc_w = (const float*)d_in[5];
    const float* fc_b = (const float*)d_in[6];
    float* out = (float*)d_out;

    const int batch  = in_sizes[0] / 32;   // 1048576
    const int nPairs = batch / 32;         // 32768 tile-pairs (2 x 16 rows)

    // 768 blocks x 512 thr: 3 blocks/CU by LDS (131KB), launch_bounds(512,4)
    // keeps the allocator at the no-spill cap.  6144 waves, ~5.3 pairs/wave.
    gru_fused<<<768, NT, 0, stream>>>(x, w_ih, b_ih, b_hh, fc_w, fc_b, out, nPairs);
}